// Round 7
// baseline (841.080 us; speedup 1.0000x reference)
//
#include <hip/hip_runtime.h>
#include <cstdint>
#include <cstddef>

#define HID   1024
#define G4    4096
#define BB    64
#define TSEQ  128
#define NSTEP 127
#define AGT   __HIP_MEMORY_SCOPE_AGENT

typedef __attribute__((ext_vector_type(4))) float f32x4;
typedef __attribute__((ext_vector_type(8))) short bf16x8;

__device__ __forceinline__ unsigned short f2bf(float x) {
  union { float f; unsigned u; } v; v.f = x;
  unsigned r = v.u + 0x7FFF + ((v.u >> 16) & 1);   // RNE
  return (unsigned short)(r >> 16);
}
__device__ __forceinline__ float fsigm(float x) { return 1.0f / (1.0f + __expf(-x)); }
__device__ __forceinline__ float ftanh(float x) { return 2.0f / (1.0f + __expf(-2.0f * x)) - 1.0f; }

// ---------------------------------------------------------------------------
__global__ __launch_bounds__(256) void conv_f32_bf16(
    const float* __restrict__ in, unsigned short* __restrict__ out, int n)
{
  int i = (blockIdx.x * 256 + threadIdx.x) * 8;
  if (i >= n) return;
  float4 v0 = *reinterpret_cast<const float4*>(&in[i]);
  float4 v1 = *reinterpret_cast<const float4*>(&in[i + 4]);
  unsigned short u[8];
  u[0] = f2bf(v0.x); u[1] = f2bf(v0.y); u[2] = f2bf(v0.z); u[3] = f2bf(v0.w);
  u[4] = f2bf(v1.x); u[5] = f2bf(v1.y); u[6] = f2bf(v1.z); u[7] = f2bf(v1.w);
  *reinterpret_cast<bf16x8*>(&out[i]) = *reinterpret_cast<bf16x8*>(u);
}

__global__ __launch_bounds__(256) void bias_add(
    const float* __restrict__ b_ih, const float* __restrict__ b_hh,
    float* __restrict__ bias)
{
  int i = blockIdx.x * 256 + threadIdx.x;
  if (i < G4) bias[i] = b_ih[i] + b_hh[i];
}

// h0 -> tagged words {tag=0 | 2xbf16}
__global__ __launch_bounds__(256) void conv_h0(
    const float* __restrict__ h0, unsigned long long* __restrict__ hb)
{
  int i = blockIdx.x * 256 + threadIdx.x;   // word idx [0, 32768)
  if (i >= BB * HID / 2) return;
  unsigned lo = f2bf(h0[2 * i]);
  unsigned hi = f2bf(h0[2 * i + 1]);
  hb[i] = (unsigned long long)(lo | (hi << 16));   // tag 0 in high 32
}

// ---------------------------------------------------------------------------
// Gather embedding rows for steps [t0, t0+tc) -> bf16 x [tc*64][HID].
// ---------------------------------------------------------------------------
__global__ __launch_bounds__(256) void conv_A(
    const int* __restrict__ tgt, const float* __restrict__ emb,
    unsigned short* __restrict__ A, int t0, int tc)
{
  int i = blockIdx.x * 256 + threadIdx.x;
  int m  = i >> 7;
  int k8 = (i & 127) * 8;
  int tl = m >> 6, b = m & 63;
  float4 v0 = make_float4(0.f, 0.f, 0.f, 0.f), v1 = v0;
  if (tl < tc) {
    int tok = tgt[b * TSEQ + t0 + tl];
    if (tok != 0) {
      const float* src = &emb[(size_t)tok * HID + k8];
      v0 = *reinterpret_cast<const float4*>(src);
      v1 = *reinterpret_cast<const float4*>(src + 4);
    }
  }
  unsigned short u[8];
  u[0] = f2bf(v0.x); u[1] = f2bf(v0.y); u[2] = f2bf(v0.z); u[3] = f2bf(v0.w);
  u[4] = f2bf(v1.x); u[5] = f2bf(v1.y); u[6] = f2bf(v1.z); u[7] = f2bf(v1.w);
  *reinterpret_cast<bf16x8*>(&A[(size_t)m * HID + k8]) = *reinterpret_cast<bf16x8*>(u);
}

// ---------------------------------------------------------------------------
// Persistent fused LSTM. 256 blocks = 4 batch-groups x 64 unit-blocks.
// Per step, per block (16 batches x 16 units):
//   - issue w_hh fragment loads (L2/L3-hot, hidden under producer latency)
//   - x-part MFMAs: x_t @ w_ih_slice (w_ih resident in 128 KB LDS)
//   - BATCHED data-as-flag poll: all 32 tagged h words loaded per round in
//     ONE parallel burst (1 L3 RTT/round), OR-reduced tag check, retry
//   - h-part MFMAs on the loaded registers, LDS cross-wave reduce,
//     activations (c in register), publish h_{t+1} as tagged 8B words
// ---------------------------------------------------------------------------
__global__ __launch_bounds__(256, 1) void lstm_persist(
    const unsigned short* __restrict__ whh, const unsigned short* __restrict__ wih,
    const unsigned short* __restrict__ xbf, const float* __restrict__ bias,
    unsigned long long* __restrict__ hb0, unsigned long long* __restrict__ hb1,
    float* __restrict__ c_ws, const float* __restrict__ c0,
    float* __restrict__ out, int t0, int tc)
{
  __shared__ unsigned short wi_lds[4 * 4 * 8 * 512];   // [w][g][kk][l*8] = 128 KB
  __shared__ float red[4][4][16][16];                   // 16 KB  (total 144 KB)

  const int tid = threadIdx.x;
  const int l = tid & 63, w = tid >> 6;
  const int lr = l & 15, lh = l >> 4;
  const int grp = blockIdx.x >> 6;      // batch group [0,4)
  const int ub  = blockIdx.x & 63;      // unit block  [0,64)
  const int b0 = grp * 16;
  const int u0 = ub * 16;

  // --- stage w_ih slice into LDS (once): 8192 x 16B chunks ---
  for (int idx = tid; idx < 8192; idx += 256) {
    int ll = idx & 63, kk = (idx >> 6) & 7, g = (idx >> 9) & 3, ww = (idx >> 11) & 3;
    bf16x8 v = *reinterpret_cast<const bf16x8*>(
        &wih[(size_t)(g * HID + u0 + (ll & 15)) * HID + ww * 256 + kk * 32 + (ll >> 4) * 8]);
    *reinterpret_cast<bf16x8*>(&wi_lds[(size_t)idx * 8]) = v;
  }

  const int bi = tid >> 4, ui = tid & 15;
  const size_t ci = (size_t)(b0 + bi) * HID + u0 + ui;
  float c_reg = (t0 == 0) ? c0[ci] : c_ws[ci];

  float bias_r[4];
#pragma unroll
  for (int g = 0; g < 4; ++g) bias_r[g] = bias[g * HID + u0 + ui];

  __syncthreads();   // LDS staged

  const size_t hbase = (size_t)(b0 + lr) * 512 + w * 128 + lh * 4;

  for (int tl = 0; tl < tc; ++tl) {
    const int t = t0 + tl;
    const unsigned long long* hin = (t & 1) ? hb1 : hb0;
    unsigned long long*       hout = (t & 1) ? hb0 : hb1;
    const unsigned tagu = (unsigned)t;

    // --- issue w_hh fragment loads early (consumed after the poll) ---
    bf16x8 bw[4][8];
#pragma unroll
    for (int g = 0; g < 4; ++g)
#pragma unroll
      for (int kk = 0; kk < 8; ++kk)
        bw[g][kk] = *reinterpret_cast<const bf16x8*>(
            &whh[(size_t)(g * HID + u0 + lr) * HID + w * 256 + kk * 32 + lh * 8]);

    // --- x-part: acc = x_t @ w_ih_slice (hides under producer latency) ---
    f32x4 acc[4];
#pragma unroll
    for (int g = 0; g < 4; ++g) acc[g] = (f32x4)0.f;
#pragma unroll
    for (int kk = 0; kk < 8; ++kk) {
      bf16x8 ax = *reinterpret_cast<const bf16x8*>(
          &xbf[((size_t)tl * BB + b0 + lr) * HID + w * 256 + kk * 32 + lh * 8]);
#pragma unroll
      for (int g = 0; g < 4; ++g) {
        bf16x8 bi2 = *reinterpret_cast<const bf16x8*>(
            &wi_lds[(size_t)(((w * 4 + g) * 8 + kk) * 512 + l * 8)]);
        acc[g] = __builtin_amdgcn_mfma_f32_16x16x32_bf16(ax, bi2, acc[g], 0, 0, 0);
      }
    }

    // --- BATCHED poll: all 32 words per round, one vmcnt drain = 1 RTT ---
    unsigned long long q[8][4];
    for (;;) {
#pragma unroll
      for (int kk = 0; kk < 8; ++kk)
#pragma unroll
        for (int j = 0; j < 4; ++j)
          q[kk][j] = __hip_atomic_load(hin + hbase + kk * 16 + j,
                                       __ATOMIC_RELAXED, AGT);
      unsigned bad = 0;
#pragma unroll
      for (int kk = 0; kk < 8; ++kk)
#pragma unroll
        for (int j = 0; j < 4; ++j)
          bad |= ((unsigned)(q[kk][j] >> 32)) ^ tagu;
      if (__all(bad == 0)) break;
    }

    // --- h-part MFMAs on loaded registers ---
#pragma unroll
    for (int kk = 0; kk < 8; ++kk) {
      union { unsigned u[4]; bf16x8 v; } ua;
      ua.u[0] = (unsigned)q[kk][0]; ua.u[1] = (unsigned)q[kk][1];
      ua.u[2] = (unsigned)q[kk][2]; ua.u[3] = (unsigned)q[kk][3];
      bf16x8 af = ua.v;
#pragma unroll
      for (int g = 0; g < 4; ++g)
        acc[g] = __builtin_amdgcn_mfma_f32_16x16x32_bf16(af, bw[g][kk], acc[g], 0, 0, 0);
    }

    // --- cross-wave K reduce ---
#pragma unroll
    for (int g = 0; g < 4; ++g)
#pragma unroll
      for (int r = 0; r < 4; ++r)
        red[w][g][lh * 4 + r][lr] = acc[g][r];
    __syncthreads();

    float gates[4];
#pragma unroll
    for (int g = 0; g < 4; ++g)
      gates[g] = red[0][g][bi][ui] + red[1][g][bi][ui] +
                 red[2][g][bi][ui] + red[3][g][bi][ui] + bias_r[g];

    float iv = fsigm(gates[0]);
    float fv = fsigm(gates[1]);
    float gv = ftanh(gates[2]);
    float ov = fsigm(gates[3]);
    c_reg = fv * c_reg + iv * gv;
    float hn = ov * ftanh(c_reg);

    // --- publish h_{t+1}: tagged 8B word per bf16 pair (FIRST, then out) ---
    unsigned hv = (unsigned)f2bf(hn);
    unsigned pv = (unsigned)__shfl_xor((int)hv, 1);
    if ((tid & 1) == 0) {
      unsigned word = (hv & 0xffffu) | (pv << 16);
      __hip_atomic_store(&hout[ci >> 1],
                         ((unsigned long long)(unsigned)(t + 1) << 32) | word,
                         __ATOMIC_RELAXED, AGT);
    }

    out[((size_t)(b0 + bi) * NSTEP + t) * HID + u0 + ui] = hn;
    if (t == NSTEP - 1) {
      size_t tail = (size_t)BB * NSTEP * HID;
      out[tail + ci] = hn;                        // h_n
      out[tail + (size_t)BB * HID + ci] = c_reg;  // c_n
    }

    __syncthreads();   // protect red[] reuse next step
  }
  c_ws[ci] = c_reg;
}

// ---------------------------------------------------------------------------
extern "C" void kernel_launch(void* const* d_in, const int* in_sizes, int n_in,
                              void* d_out, int out_size, void* d_ws, size_t ws_size,
                              hipStream_t stream)
{
  const int*   tgt  = (const int*)d_in[0];
  const float* h0   = (const float*)d_in[1];
  const float* c0   = (const float*)d_in[2];
  const float* emb  = (const float*)d_in[5];
  const float* w_ih = (const float*)d_in[6];
  const float* w_hh = (const float*)d_in[7];
  const float* b_ih = (const float*)d_in[8];
  const float* b_hh = (const float*)d_in[9];
  float* out = (float*)d_out;

  char* p = (char*)d_ws;
  unsigned short*     wih_bf = (unsigned short*)p;     p += (size_t)G4 * HID * 2;
  unsigned short*     whh_bf = (unsigned short*)p;     p += (size_t)G4 * HID * 2;
  float*              bias   = (float*)p;              p += (size_t)G4 * 4;
  unsigned long long* hb0    = (unsigned long long*)p; p += (size_t)BB * HID / 2 * 8;
  unsigned long long* hb1    = (unsigned long long*)p; p += (size_t)BB * HID / 2 * 8;
  float*              c_ws   = (float*)p;              p += (size_t)BB * HID * 4;

  size_t fixed = (size_t)(p - (char*)d_ws);
  size_t rem = (ws_size > fixed) ? ws_size - fixed : 0;
  int Tc = (int)(rem / ((size_t)BB * HID * 2));   // x chunk bytes per step
  if (Tc > NSTEP) Tc = NSTEP;
  if (Tc < 1) return;
  unsigned short* x_bf = (unsigned short*)p;

  conv_f32_bf16<<<dim3((G4 * HID) / 8 / 256), 256, 0, stream>>>(w_ih, wih_bf, G4 * HID);
  conv_f32_bf16<<<dim3((G4 * HID) / 8 / 256), 256, 0, stream>>>(w_hh, whh_bf, G4 * HID);
  bias_add<<<dim3(G4 / 256), 256, 0, stream>>>(b_ih, b_hh, bias);
  conv_h0<<<dim3(BB * HID / 2 / 256), 256, 0, stream>>>(h0, hb0);

  for (int t0 = 0; t0 < NSTEP; t0 += Tc) {
    int tc = (NSTEP - t0 < Tc) ? (NSTEP - t0) : Tc;
    conv_A<<<dim3(tc * 32), 256, 0, stream>>>(tgt, emb, x_bf, t0, tc);

    void* kargs[] = { (void*)&whh_bf, (void*)&wih_bf, (void*)&x_bf, (void*)&bias,
                      (void*)&hb0, (void*)&hb1, (void*)&c_ws, (void*)&c0,
                      (void*)&out, (void*)&t0, (void*)&tc };
    hipLaunchCooperativeKernel((void*)lstm_persist, dim3(256), dim3(256),
                               kargs, 0, stream);
  }
}

// Round 8
// 668.795 us; speedup vs baseline: 1.2576x; 1.2576x over previous
//
#include <hip/hip_runtime.h>
#include <cstdint>
#include <cstddef>

#define HID   1024
#define G4    4096
#define BB    64
#define TSEQ  128
#define NSTEP 127
#define AGT   __HIP_MEMORY_SCOPE_AGENT

typedef __attribute__((ext_vector_type(4))) float f32x4;
typedef __attribute__((ext_vector_type(8))) short bf16x8;

__device__ __forceinline__ unsigned short f2bf(float x) {
  union { float f; unsigned u; } v; v.f = x;
  unsigned r = v.u + 0x7FFF + ((v.u >> 16) & 1);   // RNE
  return (unsigned short)(r >> 16);
}
__device__ __forceinline__ float fsigm(float x) { return 1.0f / (1.0f + __expf(-x)); }
__device__ __forceinline__ float ftanh(float x) { return 2.0f / (1.0f + __expf(-2.0f * x)) - 1.0f; }

// ---------------------------------------------------------------------------
__global__ __launch_bounds__(256) void conv_f32_bf16(
    const float* __restrict__ in, unsigned short* __restrict__ out, int n)
{
  int i = (blockIdx.x * 256 + threadIdx.x) * 8;
  if (i >= n) return;
  float4 v0 = *reinterpret_cast<const float4*>(&in[i]);
  float4 v1 = *reinterpret_cast<const float4*>(&in[i + 4]);
  unsigned short u[8];
  u[0] = f2bf(v0.x); u[1] = f2bf(v0.y); u[2] = f2bf(v0.z); u[3] = f2bf(v0.w);
  u[4] = f2bf(v1.x); u[5] = f2bf(v1.y); u[6] = f2bf(v1.z); u[7] = f2bf(v1.w);
  *reinterpret_cast<bf16x8*>(&out[i]) = *reinterpret_cast<bf16x8*>(u);
}

__global__ __launch_bounds__(256) void bias_add(
    const float* __restrict__ b_ih, const float* __restrict__ b_hh,
    float* __restrict__ bias)
{
  int i = blockIdx.x * 256 + threadIdx.x;
  if (i < G4) bias[i] = b_ih[i] + b_hh[i];
}

// ---------------------------------------------------------------------------
// Gather embedding rows for steps [t0, t0+tc) -> bf16 x [tc*64][HID].
// ---------------------------------------------------------------------------
__global__ __launch_bounds__(256) void conv_A(
    const int* __restrict__ tgt, const float* __restrict__ emb,
    unsigned short* __restrict__ A, int t0, int tc)
{
  int i = blockIdx.x * 256 + threadIdx.x;
  int m  = i >> 7;
  int k8 = (i & 127) * 8;
  int tl = m >> 6, b = m & 63;
  float4 v0 = make_float4(0.f, 0.f, 0.f, 0.f), v1 = v0;
  if (tl < tc) {
    int tok = tgt[b * TSEQ + t0 + tl];
    if (tok != 0) {
      const float* src = &emb[(size_t)tok * HID + k8];
      v0 = *reinterpret_cast<const float4*>(src);
      v1 = *reinterpret_cast<const float4*>(src + 4);
    }
  }
  unsigned short u[8];
  u[0] = f2bf(v0.x); u[1] = f2bf(v0.y); u[2] = f2bf(v0.z); u[3] = f2bf(v0.w);
  u[4] = f2bf(v1.x); u[5] = f2bf(v1.y); u[6] = f2bf(v1.z); u[7] = f2bf(v1.w);
  *reinterpret_cast<bf16x8*>(&A[(size_t)m * HID + k8]) = *reinterpret_cast<bf16x8*>(u);
}

// ---------------------------------------------------------------------------
// Persistent fused LSTM. 256 blocks = 4 batch-groups x 64 unit-blocks.
// Sync per step = R5's proven two-phase scheme: per-block FLAG (cheap poll:
// 64 lanes x 4B = 256 B/round) gates ONE bulk h load (16 KB/block).
// Fused x-part (from R6): w_ih slice resident in 128 KB LDS, x_t @ w_ih
// MFMAs run BEFORE the poll (overlap producer tail). w_hh fragment loads
// are issued before the poll so they're in flight during the spin.
// ---------------------------------------------------------------------------
__global__ __launch_bounds__(256, 1) void lstm_persist(
    const unsigned short* __restrict__ whh, const unsigned short* __restrict__ wih,
    const unsigned short* __restrict__ xbf, const float* __restrict__ bias,
    unsigned int* __restrict__ hb0, unsigned int* __restrict__ hb1,
    float* __restrict__ c_ws, const float* __restrict__ c0,
    float* __restrict__ out, unsigned int* __restrict__ flags,
    int t0, int tc)
{
  __shared__ unsigned short wi_lds[4 * 4 * 8 * 512];   // 128 KB
  __shared__ float red[4][4][16][16];                   // 16 KB

  const int tid = threadIdx.x;
  const int l = tid & 63, w = tid >> 6;
  const int lr = l & 15, lh = l >> 4;
  const int grp = blockIdx.x >> 6;      // batch group [0,4)
  const int ub  = blockIdx.x & 63;      // unit block  [0,64)
  const int b0 = grp * 16;
  const int u0 = ub * 16;

  // --- stage w_ih slice into LDS (once) ---
  for (int idx = tid; idx < 8192; idx += 256) {
    int ll = idx & 63, kk = (idx >> 6) & 7, g = (idx >> 9) & 3, ww = (idx >> 11) & 3;
    bf16x8 v = *reinterpret_cast<const bf16x8*>(
        &wih[(size_t)(g * HID + u0 + (ll & 15)) * HID + ww * 256 + kk * 32 + (ll >> 4) * 8]);
    *reinterpret_cast<bf16x8*>(&wi_lds[(size_t)idx * 8]) = v;
  }

  const int bi = tid >> 4, ui = tid & 15;
  const size_t ci = (size_t)(b0 + bi) * HID + u0 + ui;
  float c_reg = (t0 == 0) ? c0[ci] : c_ws[ci];

  float bias_r[4];
#pragma unroll
  for (int g = 0; g < 4; ++g) bias_r[g] = bias[g * HID + u0 + ui];

  __syncthreads();   // LDS staged

  const size_t hbase = ((size_t)(b0 + lr) * HID) >> 1;   // word base of batch row

  for (int tl = 0; tl < tc; ++tl) {
    const int t = t0 + tl;
    const unsigned int* hin  = (t & 1) ? hb1 : hb0;
    unsigned int*       hout = (t & 1) ? hb0 : hb1;

    // --- issue w_hh fragment loads early (in flight during poll) ---
    bf16x8 bw[4][8];
#pragma unroll
    for (int g = 0; g < 4; ++g)
#pragma unroll
      for (int kk = 0; kk < 8; ++kk)
        bw[g][kk] = *reinterpret_cast<const bf16x8*>(
            &whh[(size_t)(g * HID + u0 + lr) * HID + w * 256 + kk * 32 + lh * 8]);

    // --- x-part: acc = x_t @ w_ih_slice (overlaps producer tail) ---
    f32x4 acc[4];
#pragma unroll
    for (int g = 0; g < 4; ++g) acc[g] = (f32x4)0.f;
#pragma unroll
    for (int kk = 0; kk < 8; ++kk) {
      bf16x8 ax = *reinterpret_cast<const bf16x8*>(
          &xbf[((size_t)tl * BB + b0 + lr) * HID + w * 256 + kk * 32 + lh * 8]);
#pragma unroll
      for (int g = 0; g < 4; ++g) {
        bf16x8 bi2 = *reinterpret_cast<const bf16x8*>(
            &wi_lds[(size_t)(((w * 4 + g) * 8 + kk) * 512 + l * 8)]);
        acc[g] = __builtin_amdgcn_mfma_f32_16x16x32_bf16(ax, bi2, acc[g], 0, 0, 0);
      }
    }

    // --- cheap flag poll: lane l watches producer block l of this group ---
    if (t > 0) {
      const unsigned int* fl = flags + (((size_t)(t - 1) * 4 + grp) * 64 + l) * 4;
      while (true) {
        unsigned v = __hip_atomic_load(fl, __ATOMIC_RELAXED, AGT);
        if (__all(v != 0)) break;
        __builtin_amdgcn_s_sleep(2);
      }
    }

    // --- bulk h load (one shot, L3-direct) ---
#pragma unroll
    for (int kk = 0; kk < 8; ++kk) {
      size_t base = hbase + (size_t)w * 128 + kk * 16 + lh * 4;
      unsigned long long lo = __hip_atomic_load(
          reinterpret_cast<const unsigned long long*>(&hin[base]), __ATOMIC_RELAXED, AGT);
      unsigned long long hi = __hip_atomic_load(
          reinterpret_cast<const unsigned long long*>(&hin[base + 2]), __ATOMIC_RELAXED, AGT);
      union { unsigned long long q[2]; bf16x8 v; } u;
      u.q[0] = lo; u.q[1] = hi;
      bf16x8 af = u.v;
#pragma unroll
      for (int g = 0; g < 4; ++g)
        acc[g] = __builtin_amdgcn_mfma_f32_16x16x32_bf16(af, bw[g][kk], acc[g], 0, 0, 0);
    }

    // --- cross-wave K reduce ---
#pragma unroll
    for (int g = 0; g < 4; ++g)
#pragma unroll
      for (int r = 0; r < 4; ++r)
        red[w][g][lh * 4 + r][lr] = acc[g][r];
    __syncthreads();

    float gates[4];
#pragma unroll
    for (int g = 0; g < 4; ++g)
      gates[g] = red[0][g][bi][ui] + red[1][g][bi][ui] +
                 red[2][g][bi][ui] + red[3][g][bi][ui] + bias_r[g];

    float iv = fsigm(gates[0]);
    float fv = fsigm(gates[1]);
    float gv = ftanh(gates[2]);
    float ov = fsigm(gates[3]);
    c_reg = fv * c_reg + iv * gv;
    float hn = ov * ftanh(c_reg);

    // --- publish h_{t+1} FIRST (L3-direct), then barrier-drain, then flag ---
    unsigned hv = (unsigned)f2bf(hn);
    unsigned pv = (unsigned)__shfl_xor((int)hv, 1);
    if ((tid & 1) == 0) {
      unsigned word = (hv & 0xffffu) | (pv << 16);
      __hip_atomic_store(&hout[ci >> 1], word, __ATOMIC_RELAXED, AGT);
    }

    // drain publishes, then single flag store; out-store AFTER the flag so
    // the HBM write latency is off the sync critical path
    asm volatile("s_waitcnt vmcnt(0)");
    __syncthreads();
    if (tid == 0)
      __hip_atomic_store(&flags[(((size_t)t * 4 + grp) * 64 + ub) * 4], 1u,
                         __ATOMIC_RELAXED, AGT);

    out[((size_t)(b0 + bi) * NSTEP + t) * HID + u0 + ui] = hn;
    if (t == NSTEP - 1) {
      size_t tail = (size_t)BB * NSTEP * HID;
      out[tail + ci] = hn;                        // h_n
      out[tail + (size_t)BB * HID + ci] = c_reg;  // c_n
    }
  }
  c_ws[ci] = c_reg;
}

// ---------------------------------------------------------------------------
extern "C" void kernel_launch(void* const* d_in, const int* in_sizes, int n_in,
                              void* d_out, int out_size, void* d_ws, size_t ws_size,
                              hipStream_t stream)
{
  const int*   tgt  = (const int*)d_in[0];
  const float* h0   = (const float*)d_in[1];
  const float* c0   = (const float*)d_in[2];
  const float* emb  = (const float*)d_in[5];
  const float* w_ih = (const float*)d_in[6];
  const float* w_hh = (const float*)d_in[7];
  const float* b_ih = (const float*)d_in[8];
  const float* b_hh = (const float*)d_in[9];
  float* out = (float*)d_out;

  const size_t FLAGS_BYTES = (size_t)NSTEP * 4 * 64 * 16;

  char* p = (char*)d_ws;
  unsigned short* wih_bf = (unsigned short*)p;  p += (size_t)G4 * HID * 2;
  unsigned short* whh_bf = (unsigned short*)p;  p += (size_t)G4 * HID * 2;
  float*          bias   = (float*)p;           p += (size_t)G4 * 4;
  unsigned int*   hb0    = (unsigned int*)p;    p += (size_t)BB * HID * 2;
  unsigned int*   hb1    = (unsigned int*)p;    p += (size_t)BB * HID * 2;
  float*          c_ws   = (float*)p;           p += (size_t)BB * HID * 4;
  unsigned int*   flags  = (unsigned int*)p;    p += FLAGS_BYTES;

  size_t fixed = (size_t)(p - (char*)d_ws);
  size_t rem = (ws_size > fixed) ? ws_size - fixed : 0;
  int Tc = (int)(rem / ((size_t)BB * HID * 2));
  if (Tc > NSTEP) Tc = NSTEP;
  if (Tc < 1) return;
  unsigned short* x_bf = (unsigned short*)p;

  hipMemsetAsync(flags, 0, FLAGS_BYTES, stream);
  conv_f32_bf16<<<dim3((G4 * HID) / 8 / 256), 256, 0, stream>>>(w_ih, wih_bf, G4 * HID);
  conv_f32_bf16<<<dim3((G4 * HID) / 8 / 256), 256, 0, stream>>>(w_hh, whh_bf, G4 * HID);
  bias_add<<<dim3(G4 / 256), 256, 0, stream>>>(b_ih, b_hh, bias);
  conv_f32_bf16<<<dim3((BB * HID) / 8 / 256), 256, 0, stream>>>(h0, (unsigned short*)hb0, BB * HID);

  for (int t0 = 0; t0 < NSTEP; t0 += Tc) {
    int tc = (NSTEP - t0 < Tc) ? (NSTEP - t0) : Tc;
    conv_A<<<dim3(tc * 32), 256, 0, stream>>>(tgt, emb, x_bf, t0, tc);

    void* kargs[] = { (void*)&whh_bf, (void*)&wih_bf, (void*)&x_bf, (void*)&bias,
                      (void*)&hb0, (void*)&hb1, (void*)&c_ws, (void*)&c0,
                      (void*)&out, (void*)&flags, (void*)&t0, (void*)&tc };
    hipLaunchCooperativeKernel((void*)lstm_persist, dim3(256), dim3(256),
                               kargs, 0, stream);
  }
}